// Round 9
// baseline (216.664 us; speedup 1.0000x reference)
//
#include <hip/hip_runtime.h>

#define S_LEN 4096
#define NH 16
#define DH 64
#define NE 1024

typedef __bf16 bf16_t;
typedef __bf16 bf16x8 __attribute__((ext_vector_type(8)));
typedef __bf16 bf16x4 __attribute__((ext_vector_type(4)));
typedef __bf16 bf16x2 __attribute__((ext_vector_type(2)));
typedef float  f32x4  __attribute__((ext_vector_type(4)));

#define QSCALE 0.180336879f  // 0.125 * log2(e): softmax in exp2 domain

// ---------------------------------------------------------------------------
// Fused pack kernel. Blocks [0,4096): q,k -> head-major bf16 (q pre-scaled
// QSCALE) + W -> bf16. Blocks [4096,5120): V -> vt[h][d][t] transpose via LDS.
// ---------------------------------------------------------------------------
__global__ __launch_bounds__(256) void pack_all(const float* __restrict__ q,
                                                const float* __restrict__ k,
                                                const float* __restrict__ w,
                                                const float* __restrict__ v,
                                                bf16_t* __restrict__ qb,
                                                bf16_t* __restrict__ kb,
                                                bf16_t* __restrict__ wb,
                                                bf16_t* __restrict__ vt) {
    __shared__ bf16_t tile[64][65];
    const int bid = blockIdx.x;
    if (bid < 4096) {
        const int tid = bid * 256 + threadIdx.x;
        const int e = tid * 4;
        const int s = e >> 10;
        const int c = e & (NE - 1);
        const int h = c >> 6;
        const int d = c & (DH - 1);
        const int o = (h * S_LEN + s) * DH + d;
        float4 qv = *(const float4*)(q + e);
        float4 kv = *(const float4*)(k + e);
        bf16x4 qo, ko;
        qo[0] = (bf16_t)(qv.x * QSCALE); qo[1] = (bf16_t)(qv.y * QSCALE);
        qo[2] = (bf16_t)(qv.z * QSCALE); qo[3] = (bf16_t)(qv.w * QSCALE);
        ko[0] = (bf16_t)kv.x; ko[1] = (bf16_t)kv.y; ko[2] = (bf16_t)kv.z; ko[3] = (bf16_t)kv.w;
        *(bf16x4*)(qb + o) = qo;
        *(bf16x4*)(kb + o) = ko;
        if (tid < (NE * NE / 4)) {
            float4 wv = *(const float4*)(w + tid * 4);
            bf16x4 wo;
            wo[0] = (bf16_t)wv.x; wo[1] = (bf16_t)wv.y; wo[2] = (bf16_t)wv.z; wo[3] = (bf16_t)wv.w;
            *(bf16x4*)(wb + tid * 4) = wo;
        }
    } else {
        const int vb = bid - 4096;
        const int h  = vb >> 6;
        const int t0 = (vb & 63) * 64;
        const int r  = threadIdx.x >> 6;
        const int cl = threadIdx.x & 63;
#pragma unroll
        for (int rep = 0; rep < 16; ++rep) {
            int i = rep * 4 + r;
            tile[cl][i] = (bf16_t)v[(t0 + i) * NE + h * DH + cl];
        }
        __syncthreads();
        const int r2  = threadIdx.x >> 5;
        const int cl2 = (threadIdx.x & 31) * 2;
#pragma unroll
        for (int rep = 0; rep < 8; ++rep) {
            int d = rep * 8 + r2;
            bf16x2 out;
            out[0] = tile[d][cl2];
            out[1] = tile[d][cl2 + 1];
            *(bf16x2*)(vt + (h * DH + d) * S_LEN + t0 + cl2) = out;
        }
    }
}

// ---------------------------------------------------------------------------
// Flash attention v9: 1024-thread blocks (16 waves), 256-row stiles,
// 32 waves/CU (2 blocks x 16 waves; LDS 73.7 KB, VGPR<=64 via bounds(1024,8)).
// Work: pair (p, 15-p) has 4p+4 + 64-4p = 68 key-tiles; 4 blocks take windows
// of 17 from the concatenated list (<=2 phases each). Partials -> 4 slots;
// combine sums statically-known contributors. K staged by waves 0-7, V by
// waves 8-15 (1 load + 1 LDS write per thread per tile), double-buffered,
// ONE __syncthreads per tile. lsum computed by a ones-column MFMA (no adds,
// no epilogue shuffles). Fixed-max exp2 softmax, additive fp32 partials.
// ---------------------------------------------------------------------------
__global__ __launch_bounds__(1024, 8) void attn(const bf16_t* __restrict__ qb,
                                                const bf16_t* __restrict__ kb,
                                                const bf16_t* __restrict__ vt,
                                                float* __restrict__ po,
                                                float* __restrict__ ls) {
    __shared__ __align__(16) bf16_t kbuf[2][64 * 72];
    __shared__ __align__(16) bf16_t vbuf[2][64 * 72];
    __shared__ __align__(16) bf16_t pbuf[16][16 * 72];

    const int tid  = threadIdx.x;
    const int wave = tid >> 6;        // 0..15
    const int lane = tid & 63;
    const int l15  = lane & 15;
    const int quad = lane >> 4;
    const int h = blockIdx.x;
    const int x = blockIdx.y;         // 0..31
    const int p = x >> 2;             // pair 0..7: stiles (p, 15-p)
    const int b = x & 3;              // window index within pair

    const int ns   = 4 * p + 4;       // tiles of stile p
    const int vbeg = 17 * b;          // window start in concatenated list
    int n0 = ns - vbeg;               // tiles of this window in stile p
    n0 = n0 < 0 ? 0 : (n0 > 17 ? 17 : n0);

    const bf16_t* __restrict__ qh = qb + h * (S_LEN * DH);
    const bf16_t* __restrict__ kh = kb + h * (S_LEN * DH);
    const bf16_t* __restrict__ vh = vt + h * (DH * S_LEN);

    // staging: waves 0-7 stage K, waves 8-15 stage V; 16B per thread per tile
    const int half = tid >> 9;
    const int idx  = tid & 511;
    const int row0 = idx >> 3;        // 0..63
    const int tc8  = (idx & 7) * 8;   // 0..56
    const bf16_t* sbase = half ? (vh + row0 * S_LEN + tc8) : (kh + row0 * 64 + tc8);
    const int tstep = half ? 64 : 4096;   // element offset per key-tile index
    bf16_t* dst0 = (half ? vbuf[0] : kbuf[0]) + row0 * 72 + tc8;
    bf16_t* dst1 = (half ? vbuf[1] : kbuf[1]) + row0 * 72 + tc8;

    f32x4 o_acc[4];
    f32x4 lacc;
    bf16x8 qA[2];
    int s0 = (n0 > 0 ? p * 256 : (15 - p) * 256) + wave * 16;

    const bf16_t onev = (l15 == 0) ? (bf16_t)1.0f : (bf16_t)0.0f;
    bf16x8 bOnes;
#pragma unroll
    for (int j = 0; j < 8; ++j) bOnes[j] = onev;

    auto load_q = [&](int s0_) {
#pragma unroll
        for (int dc = 0; dc < 2; ++dc)
            qA[dc] = *(const bf16x8*)(qh + (s0_ + l15) * DH + dc * 32 + quad * 8);
    };
    auto reset_acc = [&]() {
#pragma unroll
        for (int db = 0; db < 4; ++db) o_acc[db] = (f32x4){0.f, 0.f, 0.f, 0.f};
        lacc = (f32x4){0.f, 0.f, 0.f, 0.f};
    };
    auto epilogue = [&](int s0_) {
        float* poz = po + (size_t)(b * NH + h) * S_LEN * DH;
#pragma unroll
        for (int db = 0; db < 4; ++db)
#pragma unroll
            for (int r = 0; r < 4; ++r)
                poz[(s0_ + quad * 4 + r) * DH + db * 16 + l15] = o_acc[db][r];
        if (l15 == 0) {   // ones-MFMA put row-sums in col 0 (l15==0 lanes)
            float* lsz = ls + (size_t)(b * NH + h) * S_LEN;
#pragma unroll
            for (int r = 0; r < 4; ++r) lsz[s0_ + quad * 4 + r] = lacc[r];
        }
    };

    load_q(s0);
    reset_acc();

    // prologue: stage tile 0 of the window
    {
        const int t = (0 < n0) ? vbeg : vbeg - ns;
        bf16x8 r = *(const bf16x8*)(sbase + t * tstep);
        *(bf16x8*)dst0 = r;
    }
    __syncthreads();

    for (int j = 0; j < 17; ++j) {
        if (j == n0 && n0 > 0 && n0 < 17) {  // phase switch (block-uniform)
            epilogue(s0);
            s0 = (15 - p) * 256 + wave * 16;
            load_q(s0);
            reset_acc();
        }
        const int t  = (j < n0) ? vbeg + j : vbeg + j - ns;
        const int t0 = t * 64;
        const bf16_t* kb_ = kbuf[j & 1];
        const bf16_t* vb_ = vbuf[j & 1];

        // prefetch next tile global -> VGPR (lands during this tile's compute)
        bf16x8 stg;
        const bool pf = (j + 1 < 17);
        if (pf) {
            const int tn = (j + 1 < n0) ? vbeg + j + 1 : vbeg + j + 1 - ns;
            stg = *(const bf16x8*)(sbase + tn * tstep);
        }

        // QK^T: 16 rows x 64 keys per wave
        f32x4 c_[4];
#pragma unroll
        for (int ch = 0; ch < 4; ++ch) {
            bf16x8 kB0 = *(const bf16x8*)(kb_ + (ch * 16 + l15) * 72 + quad * 8);
            bf16x8 kB1 = *(const bf16x8*)(kb_ + (ch * 16 + l15) * 72 + 32 + quad * 8);
            f32x4 zr = (f32x4){0.f, 0.f, 0.f, 0.f};
            zr = __builtin_amdgcn_mfma_f32_16x16x32_bf16(qA[0], kB0, zr, 0, 0, 0);
            zr = __builtin_amdgcn_mfma_f32_16x16x32_bf16(qA[1], kB1, zr, 0, 0, 0);
            c_[ch] = zr;
        }

        if (t0 + 63 > s0) {  // causal mask (diagonal & fully-masked tiles)
#pragma unroll
            for (int ch = 0; ch < 4; ++ch) {
                int col = t0 + ch * 16 + l15;
#pragma unroll
                for (int r = 0; r < 4; ++r) {
                    int row = s0 + quad * 4 + r;
                    if (col > row) c_[ch][r] = -INFINITY;
                }
            }
        }

        // softmax: p = exp2(s' - 17); lsum comes from the ones-MFMA below
        bf16_t* pl = pbuf[wave];
#pragma unroll
        for (int ch = 0; ch < 4; ++ch)
#pragma unroll
            for (int r = 0; r < 4; ++r) {
                float pv = exp2f(c_[ch][r] - 17.0f);
                pl[(quad * 4 + r) * 72 + ch * 16 + l15] = (bf16_t)pv;
            }

        __builtin_amdgcn_wave_barrier();  // per-wave pbuf write->read order

        bf16x8 pA[2];
#pragma unroll
        for (int kc = 0; kc < 2; ++kc)
            pA[kc] = *(const bf16x8*)(pbuf[wave] + l15 * 72 + kc * 32 + quad * 8);

        bf16x8 vB[4][2];
#pragma unroll
        for (int db = 0; db < 4; ++db)
#pragma unroll
            for (int kc = 0; kc < 2; ++kc)
                vB[db][kc] = *(const bf16x8*)(vb_ + (db * 16 + l15) * 72 + kc * 32 + quad * 8);

#pragma unroll
        for (int db = 0; db < 4; ++db) {
            o_acc[db] = __builtin_amdgcn_mfma_f32_16x16x32_bf16(pA[0], vB[db][0], o_acc[db], 0, 0, 0);
            o_acc[db] = __builtin_amdgcn_mfma_f32_16x16x32_bf16(pA[1], vB[db][1], o_acc[db], 0, 0, 0);
        }
        // lsum: P x ones-column (col 0 of this acc = row sums)
        lacc = __builtin_amdgcn_mfma_f32_16x16x32_bf16(pA[0], bOnes, lacc, 0, 0, 0);
        lacc = __builtin_amdgcn_mfma_f32_16x16x32_bf16(pA[1], bOnes, lacc, 0, 0, 0);

        if (pf) {  // stage prefetched tile into the other buffer
            *(bf16x8*)((j & 1) ? dst0 : dst1) = stg;
        }
        __syncthreads();
    }

    epilogue(s0);
}

// ---------------------------------------------------------------------------
// Combine: row's output = sum of contributing slot partials / sum of lsums.
// Contributors (static per stile sigma = row>>8): pair p = min(sig,15-sig),
// ns = 4p+4; sig<8: b in [0, ceil(ns/17)); else b in [ns/17, 4).
// grid 4096 (one row per block), 256 threads x float4.
// ---------------------------------------------------------------------------
__global__ __launch_bounds__(256) void combine(const float* __restrict__ po,
                                               const float* __restrict__ ls,
                                               bf16_t* __restrict__ xb) {
    const int row = blockIdx.x;
    const int c   = threadIdx.x * 4;      // h*64 + d
    const int h   = c >> 6;
    const int d   = c & 63;
    const int sig = row >> 8;
    const int p   = (sig < 8) ? sig : 15 - sig;
    const int ns  = 4 * p + 4;
    int b_lo, b_hi;
    if (sig < 8) { b_lo = 0; b_hi = (ns + 16) / 17; }
    else         { b_lo = ns / 17; b_hi = 4; }

    float4 o = {0.f, 0.f, 0.f, 0.f};
    float l = 0.f;
    for (int bb = b_lo; bb < b_hi; ++bb) {
        const float* poz = po + ((size_t)(bb * NH + h) * S_LEN + row) * DH + d;
        float4 t = *(const float4*)poz;
        o.x += t.x; o.y += t.y; o.z += t.z; o.w += t.w;
        l += ls[(size_t)(bb * NH + h) * S_LEN + row];
    }
    float inv = 1.0f / l;
    bf16x4 out;
    out[0] = (bf16_t)(o.x * inv);
    out[1] = (bf16_t)(o.y * inv);
    out[2] = (bf16_t)(o.z * inv);
    out[3] = (bf16_t)(o.w * inv);
    *(bf16x4*)(xb + (size_t)row * NE + c) = out;
}

// ---------------------------------------------------------------------------
// Projection: Y[4096][1024] = X(bf16) @ W^T(bf16), fp32 out.
// Tile 64m x 64n, grid (64,16) = 1024 blocks; W chunk LDS double-buffered.
// ---------------------------------------------------------------------------
__global__ __launch_bounds__(256, 4) void proj(const bf16_t* __restrict__ xb,
                                               const bf16_t* __restrict__ wb,
                                               float* __restrict__ y) {
    __shared__ __align__(16) bf16_t wbuf[2][64 * 72];
    const int tid  = threadIdx.x;
    const int wave = tid >> 6;
    const int lane = tid & 63;
    const int l15  = lane & 15;
    const int quad = lane >> 4;
    const int m0 = blockIdx.x * 64 + wave * 16;
    const int n0 = blockIdx.y * 64;

    const int row0 = tid >> 3;
    const int tc8  = (tid & 7) * 8;

    f32x4 acc[4];
#pragma unroll
    for (int nb = 0; nb < 4; ++nb) acc[nb] = (f32x4){0.f, 0.f, 0.f, 0.f};

    {
        bf16x8 wr0 = *(const bf16x8*)(wb + (n0 + row0) * NE + tc8);
        bf16x8 wr1 = *(const bf16x8*)(wb + (n0 + row0 + 32) * NE + tc8);
        *(bf16x8*)(wbuf[0] + row0 * 72 + tc8) = wr0;
        *(bf16x8*)(wbuf[0] + (row0 + 32) * 72 + tc8) = wr1;
    }
    bf16x8 a[2];
#pragma unroll
    for (int kc = 0; kc < 2; ++kc)
        a[kc] = *(const bf16x8*)(xb + (m0 + l15) * NE + kc * 32 + quad * 8);
    __syncthreads();

    for (int kt = 0; kt < 16; ++kt) {
        const bf16_t* wb_ = wbuf[kt & 1];
        const bool pf = (kt + 1 < 16);
        bf16x8 wr0, wr1, an[2];
        if (pf) {
            const int kn = (kt + 1) * 64;
            wr0 = *(const bf16x8*)(wb + (n0 + row0) * NE + kn + tc8);
            wr1 = *(const bf16x8*)(wb + (n0 + row0 + 32) * NE + kn + tc8);
#pragma unroll
            for (int kc = 0; kc < 2; ++kc)
                an[kc] = *(const bf16x8*)(xb + (m0 + l15) * NE + kn + kc * 32 + quad * 8);
        }

#pragma unroll
        for (int nb = 0; nb < 4; ++nb)
#pragma unroll
            for (int kc = 0; kc < 2; ++kc) {
                bf16x8 bfrag = *(const bf16x8*)(wb_ + (nb * 16 + l15) * 72 + kc * 32 + quad * 8);
                acc[nb] = __builtin_amdgcn_mfma_f32_16x16x32_bf16(a[kc], bfrag, acc[nb], 0, 0, 0);
            }

        if (pf) {
            *(bf16x8*)(wbuf[(kt + 1) & 1] + row0 * 72 + tc8) = wr0;
            *(bf16x8*)(wbuf[(kt + 1) & 1] + (row0 + 32) * 72 + tc8) = wr1;
#pragma unroll
            for (int kc = 0; kc < 2; ++kc) a[kc] = an[kc];
        }
        __syncthreads();
    }

#pragma unroll
    for (int nb = 0; nb < 4; ++nb)
#pragma unroll
        for (int r = 0; r < 4; ++r)
            y[(m0 + quad * 4 + r) * NE + n0 + nb * 16 + l15] = acc[nb][r];
}

extern "C" void kernel_launch(void* const* d_in, const int* in_sizes, int n_in,
                              void* d_out, int out_size, void* d_ws, size_t ws_size,
                              hipStream_t stream) {
    const float* q = (const float*)d_in[0];
    const float* k = (const float*)d_in[1];
    const float* v = (const float*)d_in[2];
    const float* w = (const float*)d_in[3];
    float* y = (float*)d_out;

    // ws: bf16 {qb 4M | kb 4M | vt 4M | wb 1M | xb 4M} then fp32 {po 16.8M | ls 256K}
    bf16_t* ws = (bf16_t*)d_ws;
    bf16_t* qb = ws;
    bf16_t* kb = qb + 4 * 1024 * 1024;
    bf16_t* vt = kb + 4 * 1024 * 1024;
    bf16_t* wb = vt + 4 * 1024 * 1024;
    bf16_t* xb = wb + 1024 * 1024;
    float*  po = (float*)(xb + 4 * 1024 * 1024);
    float*  ls = po + (size_t)4 * NH * S_LEN * DH;

    pack_all<<<dim3(4096 + 1024), dim3(256), 0, stream>>>(q, k, w, v, qb, kb, wb, vt);
    attn<<<dim3(NH, 32), dim3(1024), 0, stream>>>(qb, kb, vt, po, ls);
    combine<<<dim3(4096), dim3(256), 0, stream>>>(po, ls, xb);
    proj<<<dim3(S_LEN / 64, NE / 64), dim3(256), 0, stream>>>(xb, wb, y);
}